// Round 1
// baseline (1741.593 us; speedup 1.0000x reference)
//
#include <hip/hip_runtime.h>

typedef __bf16 v8bf __attribute__((ext_vector_type(8)));
typedef float  v4f  __attribute__((ext_vector_type(4)));
typedef float  f4   __attribute__((ext_vector_type(4)));
typedef unsigned int uint;
typedef unsigned short ushort;
typedef uint   v4u  __attribute__((ext_vector_type(4)));
typedef uint   v2u  __attribute__((ext_vector_type(2)));

#define GLAS(p) ((const __attribute__((address_space(1))) void*)(p))
#define LDAS(p) ((__attribute__((address_space(3))) void*)(p))

__device__ __forceinline__ ushort f32_to_bf16(float f) {
    uint u = __builtin_bit_cast(uint, f);
    uint r = u + 0x7FFFu + ((u >> 16) & 1u);   // RNE; inputs finite
    return (ushort)(r >> 16);
}
__device__ __forceinline__ float bflo(uint v) { return __builtin_bit_cast(float, v << 16); }
__device__ __forceinline__ float bfhi(uint v) { return __builtin_bit_cast(float, v & 0xFFFF0000u); }

// ---------------- column stats (sum, sumsq) ----------------
__global__ void colstats_f32(const float* __restrict__ x, float* __restrict__ sum,
                             float* __restrict__ ssum, int ncols, int rows) {
    int c = blockIdx.x * blockDim.x + threadIdx.x;
    size_t base = (size_t)blockIdx.y * rows * ncols + c;
    float s = 0.f, q = 0.f;
#pragma unroll 4
    for (int r = 0; r < rows; ++r) {
        float v = x[base + (size_t)r * ncols];
        s += v; q += v * v;
    }
    atomicAdd(&sum[c], s);
    atomicAdd(&ssum[c], q);
}

__global__ void colstats_bf16(const ushort* __restrict__ h, float* __restrict__ sum,
                              float* __restrict__ ssum, int ncols, int rows) {
    int cp = blockIdx.x * blockDim.x + threadIdx.x;   // column pair
    int half = ncols >> 1;
    const uint* h32 = (const uint*)h;
    size_t base = (size_t)blockIdx.y * rows * half + cp;
    float s0 = 0.f, q0 = 0.f, s1 = 0.f, q1 = 0.f;
#pragma unroll 4
    for (int r = 0; r < rows; ++r) {
        uint v = h32[base + (size_t)r * half];
        float a = bflo(v), b = bfhi(v);
        s0 += a; q0 += a * a;
        s1 += b; q1 += b * b;
    }
    atomicAdd(&sum[2 * cp], s0);  atomicAdd(&ssum[2 * cp], q0);
    atomicAdd(&sum[2 * cp + 1], s1); atomicAdd(&ssum[2 * cp + 1], q1);
}

__global__ void bn_finalize(const float* __restrict__ sum, const float* __restrict__ ssum,
                            const float* __restrict__ g, const float* __restrict__ b,
                            float* __restrict__ s, float* __restrict__ t, float invN) {
    int c = blockIdx.x * blockDim.x + threadIdx.x;
    float m = sum[c] * invN;
    float var = fmaxf(ssum[c] * invN - m * m, 0.f);
    float rs = rsqrtf(var + 1e-5f);
    float sc = rs * g[c];
    s[c] = sc;
    t[c] = b[c] - m * sc;
}

// ---------------- fp32 -> bf16 convert (8 elems/thread) ----------------
__global__ void cvt_f32_bf16(const float* __restrict__ x, ushort* __restrict__ o) {
    size_t i = (size_t)blockIdx.x * blockDim.x + threadIdx.x;
    const f4* x4 = (const f4*)x;
    f4 a = x4[i * 2], b = x4[i * 2 + 1];
    union { ushort us[8]; v4u v; } p;
    p.us[0] = f32_to_bf16(a.x); p.us[1] = f32_to_bf16(a.y);
    p.us[2] = f32_to_bf16(a.z); p.us[3] = f32_to_bf16(a.w);
    p.us[4] = f32_to_bf16(b.x); p.us[5] = f32_to_bf16(b.y);
    p.us[6] = f32_to_bf16(b.z); p.us[7] = f32_to_bf16(b.w);
    ((v4u*)o)[i] = p.v;
}

// ---------------- fold BN scale/shift into weights ----------------
// Wp[j,k] = bf16(W[j,k]*s[k]);  bp[j] = bias[j] + sum_k W[j,k]*t[k]
__global__ void fold_w(const float* __restrict__ W, const float* __restrict__ bias,
                       const float* __restrict__ s, const float* __restrict__ t,
                       ushort* __restrict__ Wp, float* __restrict__ bp, int K) {
    int j = blockIdx.x, tx = threadIdx.x;
    const f4* row = (const f4*)(W + (size_t)j * K);
    const f4* s4 = (const f4*)s;
    const f4* t4 = (const f4*)t;
    v2u* orow = (v2u*)(Wp + (size_t)j * K);
    float part = 0.f;
    int K4 = K >> 2;
    for (int k = tx; k < K4; k += 256) {
        f4 v = row[k], sv = s4[k], tv = t4[k];
        part += v.x * tv.x + v.y * tv.y + v.z * tv.z + v.w * tv.w;
        union { ushort us[4]; v2u u; } o;
        o.us[0] = f32_to_bf16(v.x * sv.x);
        o.us[1] = f32_to_bf16(v.y * sv.y);
        o.us[2] = f32_to_bf16(v.z * sv.z);
        o.us[3] = f32_to_bf16(v.w * sv.w);
        orow[k] = o.u;
    }
    __shared__ float red[256];
    red[tx] = part;
    __syncthreads();
    for (int off = 128; off > 0; off >>= 1) {
        if (tx < off) red[tx] += red[tx + off];
        __syncthreads();
    }
    if (tx == 0) bp[j] = bias[j] + red[0];
}

// ---------------- bf16 MFMA GEMM, B^T layout (m97 structure) ----------------
// C[m,n] = sum_k A[m,k]*B[n,k] (+ epilogue).  128x128 tile, BK=64, 4 waves,
// each wave 64x64 via 4x4 grid of 16x16x32 MFMA.  global_load_lds width-16.
// EPI=0: out bf16 = relu(acc + bias[col])
// EPI=1: out f32  = acc + bias[col] + beta*Y[row,col]
template <int EPI>
__global__ __launch_bounds__(256) void gemm_bt(
    const ushort* __restrict__ A, const ushort* __restrict__ B,
    void* __restrict__ Cout, const float* __restrict__ bias,
    const float* __restrict__ Y, const float* __restrict__ betaPtr,
    int M, int Ncol, int K) {
    __shared__ __align__(16) ushort lsA[128 * 64];
    __shared__ __align__(16) ushort lsB[128 * 64];
    const int tid = threadIdx.x;
    const int wave = tid >> 6, lane = tid & 63;
    const int wm = wave >> 1, wn = wave & 1;
    const int lhi = lane >> 4, llo = lane & 15;
    const int m0 = blockIdx.y * 128, n0 = blockIdx.x * 128;

    v4f acc[4][4] = {};

    for (int k0 = 0; k0 < K; k0 += 64) {
#pragma unroll
        for (int q = 0; q < 4; ++q) {
            int f = ((q * 4 + wave) << 9) + lane * 8;  // flat elem offset in tile
            int r = f >> 6, c = f & 63;
            const ushort* sa = A + (size_t)(m0 + r) * K + (k0 + c);
            const ushort* sb = B + (size_t)(n0 + r) * K + (k0 + c);
            __builtin_amdgcn_global_load_lds(GLAS(sa), LDAS(&lsA[(q * 4 + wave) * 512]), 16, 0, 0);
            __builtin_amdgcn_global_load_lds(GLAS(sb), LDAS(&lsB[(q * 4 + wave) * 512]), 16, 0, 0);
        }
        __syncthreads();
#pragma unroll
        for (int kk = 0; kk < 64; kk += 32) {
            v8bf a[4], b[4];
#pragma unroll
            for (int i = 0; i < 4; ++i)
                a[i] = __builtin_bit_cast(v8bf,
                    *(const v4u*)&lsA[(wm * 64 + i * 16 + llo) * 64 + kk + lhi * 8]);
#pragma unroll
            for (int j = 0; j < 4; ++j)
                b[j] = __builtin_bit_cast(v8bf,
                    *(const v4u*)&lsB[(wn * 64 + j * 16 + llo) * 64 + kk + lhi * 8]);
#pragma unroll
            for (int i = 0; i < 4; ++i)
#pragma unroll
                for (int j = 0; j < 4; ++j)
                    acc[i][j] = __builtin_amdgcn_mfma_f32_16x16x32_bf16(a[i], b[j], acc[i][j], 0, 0, 0);
        }
        __syncthreads();
    }

    const float betaV = (EPI == 1) ? betaPtr[0] : 0.f;
#pragma unroll
    for (int j = 0; j < 4; ++j) {
        const int col = n0 + wn * 64 + j * 16 + llo;
        const float bj = bias[col];
#pragma unroll
        for (int i = 0; i < 4; ++i) {
#pragma unroll
            for (int reg = 0; reg < 4; ++reg) {
                const int row = m0 + wm * 64 + i * 16 + lhi * 4 + reg;
                float v = acc[i][j][reg] + bj;
                if (EPI == 0) {
                    v = v > 0.f ? v : 0.f;
                    ((ushort*)Cout)[(size_t)row * Ncol + col] = f32_to_bf16(v);
                } else {
                    v += betaV * Y[(size_t)row * Ncol + col];
                    ((float*)Cout)[(size_t)row * Ncol + col] = v;
                }
            }
        }
    }
}

extern "C" void kernel_launch(void* const* d_in, const int* in_sizes, int n_in,
                              void* d_out, int out_size, void* d_ws, size_t ws_size,
                              hipStream_t stream) {
    const float* x    = (const float*)d_in[0];
    const float* y    = (const float*)d_in[1];
    const float* W1   = (const float*)d_in[2];
    const float* b1   = (const float*)d_in[3];
    const float* W2   = (const float*)d_in[4];
    const float* b2   = (const float*)d_in[5];
    const float* bn1g = (const float*)d_in[6];
    const float* bn1b = (const float*)d_in[7];
    const float* bn2g = (const float*)d_in[8];
    const float* bn2b = (const float*)d_in[9];
    const float* beta = (const float*)d_in[10];

    constexpr int Nb = 32768, F = 2048, H = 4096, C = 512;

    char* w = (char*)d_ws;
    ushort* xb  = (ushort*)w;                                       // 128 MB
    ushort* h1  = (ushort*)(w + (size_t)Nb * F * 2);                // 256 MB
    ushort* w1p = (ushort*)(w + (size_t)Nb * F * 2 + (size_t)Nb * H * 2);          // 16 MB
    ushort* w2p = (ushort*)((char*)w1p + (size_t)H * F * 2);        // 4 MB
    float*  fb  = (float*)((char*)w2p + (size_t)C * H * 2);
    float* b1p = fb;            // H
    float* b2p = b1p + H;       // C
    float* sum1 = b2p + C;      // F
    float* ss1  = sum1 + F;     // F
    float* s1   = ss1 + F;      // F
    float* t1   = s1 + F;       // F
    float* sum2 = t1 + F;       // H
    float* ss2  = sum2 + H;     // H
    float* s2   = ss2 + H;      // H
    float* t2   = s2 + H;       // H

    hipMemsetAsync(sum1, 0, sizeof(float) * 2 * F, stream);
    hipMemsetAsync(sum2, 0, sizeof(float) * 2 * H, stream);

    // BN1 stats from x
    colstats_f32<<<dim3(F / 256, 64), 256, 0, stream>>>(x, sum1, ss1, F, Nb / 64);
    bn_finalize<<<F / 256, 256, 0, stream>>>(sum1, ss1, bn1g, bn1b, s1, t1, 1.f / Nb);
    // x -> bf16
    cvt_f32_bf16<<<(int)(((size_t)Nb * F / 8) / 256), 256, 0, stream>>>(x, xb);
    // fold BN1 into W1
    fold_w<<<H, 256, 0, stream>>>(W1, b1, s1, t1, w1p, b1p, F);
    // h1 = relu(xb @ w1p^T + b1p), bf16
    gemm_bt<0><<<dim3(H / 128, Nb / 128), 256, 0, stream>>>(xb, w1p, h1, b1p, nullptr, nullptr, Nb, H, F);
    // BN2 stats from h1
    colstats_bf16<<<dim3(H / 512, 64), 256, 0, stream>>>(h1, sum2, ss2, H, Nb / 64);
    bn_finalize<<<H / 256, 256, 0, stream>>>(sum2, ss2, bn2g, bn2b, s2, t2, 1.f / Nb);
    // fold BN2 into W2
    fold_w<<<C, 256, 0, stream>>>(W2, b2, s2, t2, w2p, b2p, H);
    // out = h1 @ w2p^T + b2p + beta*y, fp32
    gemm_bt<1><<<dim3(C / 128, Nb / 128), 256, 0, stream>>>(h1, w2p, d_out, b2p, y, beta, Nb, C, H);
    (void)in_sizes; (void)n_in; (void)out_size; (void)ws_size;
}

// Round 2
// 1627.429 us; speedup vs baseline: 1.0701x; 1.0701x over previous
//
#include <hip/hip_runtime.h>

typedef __bf16 v8bf __attribute__((ext_vector_type(8)));
typedef float  v4f  __attribute__((ext_vector_type(4)));
typedef float  f4   __attribute__((ext_vector_type(4)));
typedef unsigned int uint;
typedef unsigned short ushort;
typedef uint   v4u  __attribute__((ext_vector_type(4)));
typedef uint   v2u  __attribute__((ext_vector_type(2)));

#define GLAS(p) ((const __attribute__((address_space(1))) void*)(p))
#define LDAS(p) ((__attribute__((address_space(3))) void*)(p))

__device__ __forceinline__ ushort f32_to_bf16(float f) {
    uint u = __builtin_bit_cast(uint, f);
    uint r = u + 0x7FFFu + ((u >> 16) & 1u);   // RNE; inputs finite
    return (ushort)(r >> 16);
}
__device__ __forceinline__ float bflo(uint v) { return __builtin_bit_cast(float, v << 16); }
__device__ __forceinline__ float bfhi(uint v) { return __builtin_bit_cast(float, v & 0xFFFF0000u); }

// ---------------- fused BN1 column stats + fp32->bf16 convert ----------------
// Thread handles 4 adjacent columns; reads float4, writes 4xbf16 (8B).
__global__ void colstats_cvt(const float* __restrict__ x, ushort* __restrict__ xb,
                             float* __restrict__ sum, float* __restrict__ ssum,
                             int ncols, int rows) {
    int c4 = blockIdx.x * blockDim.x + threadIdx.x;   // column quad index
    int q = ncols >> 2;
    size_t base = (size_t)blockIdx.y * rows * q + c4;
    const f4* x4 = (const f4*)x;
    v2u* o = (v2u*)xb;
    f4 s = {0.f, 0.f, 0.f, 0.f}, qq = {0.f, 0.f, 0.f, 0.f};
#pragma unroll 4
    for (int r = 0; r < rows; ++r) {
        f4 v = x4[base + (size_t)r * q];
        s += v; qq += v * v;
        union { ushort us[4]; v2u u; } p;
        p.us[0] = f32_to_bf16(v.x); p.us[1] = f32_to_bf16(v.y);
        p.us[2] = f32_to_bf16(v.z); p.us[3] = f32_to_bf16(v.w);
        o[base + (size_t)r * q] = p.u;
    }
    atomicAdd(&sum[4 * c4 + 0], s.x);  atomicAdd(&ssum[4 * c4 + 0], qq.x);
    atomicAdd(&sum[4 * c4 + 1], s.y);  atomicAdd(&ssum[4 * c4 + 1], qq.y);
    atomicAdd(&sum[4 * c4 + 2], s.z);  atomicAdd(&ssum[4 * c4 + 2], qq.z);
    atomicAdd(&sum[4 * c4 + 3], s.w);  atomicAdd(&ssum[4 * c4 + 3], qq.w);
}

__global__ void colstats_bf16(const ushort* __restrict__ h, float* __restrict__ sum,
                              float* __restrict__ ssum, int ncols, int rows) {
    int cp = blockIdx.x * blockDim.x + threadIdx.x;   // column pair
    int half = ncols >> 1;
    const uint* h32 = (const uint*)h;
    size_t base = (size_t)blockIdx.y * rows * half + cp;
    float s0 = 0.f, q0 = 0.f, s1 = 0.f, q1 = 0.f;
#pragma unroll 4
    for (int r = 0; r < rows; ++r) {
        uint v = h32[base + (size_t)r * half];
        float a = bflo(v), b = bfhi(v);
        s0 += a; q0 += a * a;
        s1 += b; q1 += b * b;
    }
    atomicAdd(&sum[2 * cp], s0);  atomicAdd(&ssum[2 * cp], q0);
    atomicAdd(&sum[2 * cp + 1], s1); atomicAdd(&ssum[2 * cp + 1], q1);
}

__global__ void bn_finalize(const float* __restrict__ sum, const float* __restrict__ ssum,
                            const float* __restrict__ g, const float* __restrict__ b,
                            float* __restrict__ s, float* __restrict__ t, float invN) {
    int c = blockIdx.x * blockDim.x + threadIdx.x;
    float m = sum[c] * invN;
    float var = fmaxf(ssum[c] * invN - m * m, 0.f);
    float rs = rsqrtf(var + 1e-5f);
    float sc = rs * g[c];
    s[c] = sc;
    t[c] = b[c] - m * sc;
}

// ---------------- fold BN scale/shift into weights ----------------
// Wp[j,k] = bf16(W[j,k]*s[k]);  bp[j] = bias[j] + sum_k W[j,k]*t[k]
__global__ void fold_w(const float* __restrict__ W, const float* __restrict__ bias,
                       const float* __restrict__ s, const float* __restrict__ t,
                       ushort* __restrict__ Wp, float* __restrict__ bp, int K) {
    int j = blockIdx.x, tx = threadIdx.x;
    const f4* row = (const f4*)(W + (size_t)j * K);
    const f4* s4 = (const f4*)s;
    const f4* t4 = (const f4*)t;
    v2u* orow = (v2u*)(Wp + (size_t)j * K);
    float part = 0.f;
    int K4 = K >> 2;
    for (int k = tx; k < K4; k += 256) {
        f4 v = row[k], sv = s4[k], tv = t4[k];
        part += v.x * tv.x + v.y * tv.y + v.z * tv.z + v.w * tv.w;
        union { ushort us[4]; v2u u; } o;
        o.us[0] = f32_to_bf16(v.x * sv.x);
        o.us[1] = f32_to_bf16(v.y * sv.y);
        o.us[2] = f32_to_bf16(v.z * sv.z);
        o.us[3] = f32_to_bf16(v.w * sv.w);
        orow[k] = o.u;
    }
    __shared__ float red[256];
    red[tx] = part;
    __syncthreads();
    for (int off = 128; off > 0; off >>= 1) {
        if (tx < off) red[tx] += red[tx + off];
        __syncthreads();
    }
    if (tx == 0) bp[j] = bias[j] + red[0];
}

// ---------------- bf16 MFMA GEMM, B^T layout, XOR-swizzled LDS ----------------
// C[m,n] = sum_k A[m,k]*B[n,k] (+ epilogue).  128x128 tile, BK=64, 4 waves,
// each wave 64x64 via 4x4 grid of 16x16x32 MFMA.  global_load_lds width-16.
// LDS tile = 128 rows x 8 granules (granule = 8 bf16 = 16B).
// Granule (row,c) lives at physical granule  row*8 + (c ^ (row&7))  -> the
// fragment ds_read_b128s then spread over all 8 bank-quads (conflict-free;
// rows 8 apart share a quad = free 2-way).
// EPI=0: out bf16 = relu(acc + bias[col])
// EPI=1: out f32  = acc + bias[col] + beta*Y[row,col]
template <int EPI>
__global__ __launch_bounds__(256) void gemm_bt(
    const ushort* __restrict__ A, const ushort* __restrict__ B,
    void* __restrict__ Cout, const float* __restrict__ bias,
    const float* __restrict__ Y, const float* __restrict__ betaPtr,
    int M, int Ncol, int K) {
    __shared__ __align__(16) ushort lsA[128 * 64];
    __shared__ __align__(16) ushort lsB[128 * 64];
    const int tid = threadIdx.x;
    const int wave = tid >> 6, lane = tid & 63;
    const int wm = wave >> 1, wn = wave & 1;
    const int lhi = lane >> 4, llo = lane & 15;
    const int m0 = blockIdx.y * 128, n0 = blockIdx.x * 128;

    // Staging geometry (swizzle): lane l of issue (q,wave) writes physical
    // granule g = (q*4+wave)*64 + l, which must hold global
    // (row = g>>3, c = (g&7)^((g>>3)&7)).  Since the granule base is a
    // multiple of 64: row = base_row + (l>>3), c = (l&7)^((l>>3)&7).
    const int srow = lane >> 3;                        // 0..7 within issue
    const int sgc  = (lane & 7) ^ (lane >> 3);         // swizzled granule col 0..7

    v4f acc[4][4] = {};

    for (int k0 = 0; k0 < K; k0 += 64) {
#pragma unroll
        for (int q = 0; q < 4; ++q) {
            const int g0 = (q * 4 + wave) << 6;        // granule base (64/issue)
            const int row = (g0 >> 3) + srow;          // tile row 0..127
            const ushort* sa = A + (size_t)(m0 + row) * K + k0 + sgc * 8;
            const ushort* sb = B + (size_t)(n0 + row) * K + k0 + sgc * 8;
            __builtin_amdgcn_global_load_lds(GLAS(sa), LDAS(&lsA[g0 * 8]), 16, 0, 0);
            __builtin_amdgcn_global_load_lds(GLAS(sb), LDAS(&lsB[g0 * 8]), 16, 0, 0);
        }
        __syncthreads();
#pragma unroll
        for (int kk = 0; kk < 64; kk += 32) {
            v8bf a[4], b[4];
            const int cbase = (kk >> 3) + lhi;         // logical granule col
#pragma unroll
            for (int i = 0; i < 4; ++i) {
                const int ra = wm * 64 + i * 16 + llo;
                const int pa = ra * 8 + (cbase ^ (ra & 7));
                a[i] = __builtin_bit_cast(v8bf, *(const v4u*)&lsA[pa * 8]);
            }
#pragma unroll
            for (int j = 0; j < 4; ++j) {
                const int rb = wn * 64 + j * 16 + llo;
                const int pb = rb * 8 + (cbase ^ (rb & 7));
                b[j] = __builtin_bit_cast(v8bf, *(const v4u*)&lsB[pb * 8]);
            }
#pragma unroll
            for (int i = 0; i < 4; ++i)
#pragma unroll
                for (int j = 0; j < 4; ++j)
                    acc[i][j] = __builtin_amdgcn_mfma_f32_16x16x32_bf16(a[i], b[j], acc[i][j], 0, 0, 0);
        }
        __syncthreads();
    }

    const float betaV = (EPI == 1) ? betaPtr[0] : 0.f;
#pragma unroll
    for (int j = 0; j < 4; ++j) {
        const int col = n0 + wn * 64 + j * 16 + llo;
        const float bj = bias[col];
#pragma unroll
        for (int i = 0; i < 4; ++i) {
#pragma unroll
            for (int reg = 0; reg < 4; ++reg) {
                const int row = m0 + wm * 64 + i * 16 + lhi * 4 + reg;
                float v = acc[i][j][reg] + bj;
                if (EPI == 0) {
                    v = v > 0.f ? v : 0.f;
                    ((ushort*)Cout)[(size_t)row * Ncol + col] = f32_to_bf16(v);
                } else {
                    v += betaV * Y[(size_t)row * Ncol + col];
                    ((float*)Cout)[(size_t)row * Ncol + col] = v;
                }
            }
        }
    }
}

extern "C" void kernel_launch(void* const* d_in, const int* in_sizes, int n_in,
                              void* d_out, int out_size, void* d_ws, size_t ws_size,
                              hipStream_t stream) {
    const float* x    = (const float*)d_in[0];
    const float* y    = (const float*)d_in[1];
    const float* W1   = (const float*)d_in[2];
    const float* b1   = (const float*)d_in[3];
    const float* W2   = (const float*)d_in[4];
    const float* b2   = (const float*)d_in[5];
    const float* bn1g = (const float*)d_in[6];
    const float* bn1b = (const float*)d_in[7];
    const float* bn2g = (const float*)d_in[8];
    const float* bn2b = (const float*)d_in[9];
    const float* beta = (const float*)d_in[10];

    constexpr int Nb = 32768, F = 2048, H = 4096, C = 512;

    char* w = (char*)d_ws;
    ushort* xb  = (ushort*)w;                                       // 128 MB
    ushort* h1  = (ushort*)(w + (size_t)Nb * F * 2);                // 256 MB
    ushort* w1p = (ushort*)(w + (size_t)Nb * F * 2 + (size_t)Nb * H * 2);   // 16 MB
    ushort* w2p = (ushort*)((char*)w1p + (size_t)H * F * 2);        // 4 MB
    float*  fb  = (float*)((char*)w2p + (size_t)C * H * 2);
    float* b1p = fb;            // H
    float* b2p = b1p + H;       // C
    float* sum1 = b2p + C;      // F
    float* ss1  = sum1 + F;     // F
    float* s1   = ss1 + F;      // F
    float* t1   = s1 + F;       // F
    float* sum2 = t1 + F;       // H
    float* ss2  = sum2 + H;     // H
    float* s2   = ss2 + H;      // H
    float* t2   = s2 + H;       // H

    hipMemsetAsync(sum1, 0, sizeof(float) * 2 * F, stream);
    hipMemsetAsync(sum2, 0, sizeof(float) * 2 * H, stream);

    // BN1 stats + x->bf16 (fused): thread = 4 columns, grid (F/4/256, 64)
    colstats_cvt<<<dim3(F / 4 / 256, 64), 256, 0, stream>>>(x, xb, sum1, ss1, F, Nb / 64);
    bn_finalize<<<F / 256, 256, 0, stream>>>(sum1, ss1, bn1g, bn1b, s1, t1, 1.f / Nb);
    // fold BN1 into W1
    fold_w<<<H, 256, 0, stream>>>(W1, b1, s1, t1, w1p, b1p, F);
    // h1 = relu(xb @ w1p^T + b1p), bf16
    gemm_bt<0><<<dim3(H / 128, Nb / 128), 256, 0, stream>>>(xb, w1p, h1, b1p, nullptr, nullptr, Nb, H, F);
    // BN2 stats from h1
    colstats_bf16<<<dim3(H / 512, 64), 256, 0, stream>>>(h1, sum2, ss2, H, Nb / 64);
    bn_finalize<<<H / 256, 256, 0, stream>>>(sum2, ss2, bn2g, bn2b, s2, t2, 1.f / Nb);
    // fold BN2 into W2
    fold_w<<<C, 256, 0, stream>>>(W2, b2, s2, t2, w2p, b2p, H);
    // out = h1 @ w2p^T + b2p + beta*y, fp32
    gemm_bt<1><<<dim3(C / 128, Nb / 128), 256, 0, stream>>>(h1, w2p, d_out, b2p, y, beta, Nb, C, H);
    (void)in_sizes; (void)n_in; (void)out_size; (void)ws_size;
}

// Round 3
// 1399.423 us; speedup vs baseline: 1.2445x; 1.1629x over previous
//
#include <hip/hip_runtime.h>

typedef __bf16 v8bf __attribute__((ext_vector_type(8)));
typedef float  v16f __attribute__((ext_vector_type(16)));
typedef float  f4   __attribute__((ext_vector_type(4)));
typedef unsigned int uint;
typedef unsigned short ushort;
typedef uint   v4u  __attribute__((ext_vector_type(4)));
typedef uint   v2u  __attribute__((ext_vector_type(2)));

#define GLAS(p) ((const __attribute__((address_space(1))) void*)(p))
#define LDAS(p) ((__attribute__((address_space(3))) void*)(p))

__device__ __forceinline__ ushort f32_to_bf16(float f) {
    uint u = __builtin_bit_cast(uint, f);
    uint r = u + 0x7FFFu + ((u >> 16) & 1u);   // RNE; inputs finite
    return (ushort)(r >> 16);
}
__device__ __forceinline__ float bflo(uint v) { return __builtin_bit_cast(float, v << 16); }
__device__ __forceinline__ float bfhi(uint v) { return __builtin_bit_cast(float, v & 0xFFFF0000u); }

// ---------------- fused BN1 column stats + fp32->bf16 convert ----------------
// Thread handles 4 adjacent columns; reads float4, writes 4xbf16 (8B).
__global__ void colstats_cvt(const float* __restrict__ x, ushort* __restrict__ xb,
                             float* __restrict__ sum, float* __restrict__ ssum,
                             int ncols, int rows) {
    int c4 = blockIdx.x * blockDim.x + threadIdx.x;   // column quad index
    int q = ncols >> 2;
    size_t base = (size_t)blockIdx.y * rows * q + c4;
    const f4* x4 = (const f4*)x;
    v2u* o = (v2u*)xb;
    f4 s = {0.f, 0.f, 0.f, 0.f}, qq = {0.f, 0.f, 0.f, 0.f};
#pragma unroll 4
    for (int r = 0; r < rows; ++r) {
        f4 v = x4[base + (size_t)r * q];
        s += v; qq += v * v;
        union { ushort us[4]; v2u u; } p;
        p.us[0] = f32_to_bf16(v.x); p.us[1] = f32_to_bf16(v.y);
        p.us[2] = f32_to_bf16(v.z); p.us[3] = f32_to_bf16(v.w);
        o[base + (size_t)r * q] = p.u;
    }
    atomicAdd(&sum[4 * c4 + 0], s.x);  atomicAdd(&ssum[4 * c4 + 0], qq.x);
    atomicAdd(&sum[4 * c4 + 1], s.y);  atomicAdd(&ssum[4 * c4 + 1], qq.y);
    atomicAdd(&sum[4 * c4 + 2], s.z);  atomicAdd(&ssum[4 * c4 + 2], qq.z);
    atomicAdd(&sum[4 * c4 + 3], s.w);  atomicAdd(&ssum[4 * c4 + 3], qq.w);
}

__global__ void colstats_bf16(const ushort* __restrict__ h, float* __restrict__ sum,
                              float* __restrict__ ssum, int ncols, int rows) {
    int cp = blockIdx.x * blockDim.x + threadIdx.x;   // column pair
    int half = ncols >> 1;
    const uint* h32 = (const uint*)h;
    size_t base = (size_t)blockIdx.y * rows * half + cp;
    float s0 = 0.f, q0 = 0.f, s1 = 0.f, q1 = 0.f;
#pragma unroll 4
    for (int r = 0; r < rows; ++r) {
        uint v = h32[base + (size_t)r * half];
        float a = bflo(v), b = bfhi(v);
        s0 += a; q0 += a * a;
        s1 += b; q1 += b * b;
    }
    atomicAdd(&sum[2 * cp], s0);  atomicAdd(&ssum[2 * cp], q0);
    atomicAdd(&sum[2 * cp + 1], s1); atomicAdd(&ssum[2 * cp + 1], q1);
}

__global__ void bn_finalize(const float* __restrict__ sum, const float* __restrict__ ssum,
                            const float* __restrict__ g, const float* __restrict__ b,
                            float* __restrict__ s, float* __restrict__ t, float invN) {
    int c = blockIdx.x * blockDim.x + threadIdx.x;
    float m = sum[c] * invN;
    float var = fmaxf(ssum[c] * invN - m * m, 0.f);
    float rs = rsqrtf(var + 1e-5f);
    float sc = rs * g[c];
    s[c] = sc;
    t[c] = b[c] - m * sc;
}

// ---------------- fold BN scale/shift into weights ----------------
// Wp[j,k] = bf16(W[j,k]*s[k]);  bp[j] = bias[j] + sum_k W[j,k]*t[k]
__global__ void fold_w(const float* __restrict__ W, const float* __restrict__ bias,
                       const float* __restrict__ s, const float* __restrict__ t,
                       ushort* __restrict__ Wp, float* __restrict__ bp, int K) {
    int j = blockIdx.x, tx = threadIdx.x;
    const f4* row = (const f4*)(W + (size_t)j * K);
    const f4* s4 = (const f4*)s;
    const f4* t4 = (const f4*)t;
    v2u* orow = (v2u*)(Wp + (size_t)j * K);
    float part = 0.f;
    int K4 = K >> 2;
    for (int k = tx; k < K4; k += 256) {
        f4 v = row[k], sv = s4[k], tv = t4[k];
        part += v.x * tv.x + v.y * tv.y + v.z * tv.z + v.w * tv.w;
        union { ushort us[4]; v2u u; } o;
        o.us[0] = f32_to_bf16(v.x * sv.x);
        o.us[1] = f32_to_bf16(v.y * sv.y);
        o.us[2] = f32_to_bf16(v.z * sv.z);
        o.us[3] = f32_to_bf16(v.w * sv.w);
        orow[k] = o.u;
    }
    __shared__ float red[256];
    red[tx] = part;
    __syncthreads();
    for (int off = 128; off > 0; off >>= 1) {
        if (tx < off) red[tx] += red[tx + off];
        __syncthreads();
    }
    if (tx == 0) bp[j] = bias[j] + red[0];
}

// ---------------- bf16 MFMA GEMM, B^T layout, XOR-swizzled LDS ----------------
// C[m,n] = sum_k A[m,k]*B[n,k] (+ epilogue).  128x128 tile, BK=64, 4 waves,
// each wave 64x64 via 2x2 grid of 32x32x16 MFMA.  global_load_lds width-16.
// LDS tile = 128 rows x 8 granules (granule = 8 bf16 = 16B).
// Granule (row,c) lives at physical granule  row*8 + (c ^ (row&7)) -> fragment
// ds_read_b128s spread over all 8 bank-quads (conflict-free; 2-way is free).
// 32x32x16 A/B frag: m(or n) = lane&31, k = (lane>>5)*8 + j.
// 32x32 C/D: col = lane&31, row = (reg&3) + 8*(reg>>2) + 4*(lane>>5)  [m74/m101]
// EPI=0: out bf16 = relu(acc + bias[col])
// EPI=1: out f32  = acc + bias[col] + beta*Y[row,col]
template <int EPI>
__global__ __launch_bounds__(256) void gemm_bt(
    const ushort* __restrict__ A, const ushort* __restrict__ B,
    void* __restrict__ Cout, const float* __restrict__ bias,
    const float* __restrict__ Y, const float* __restrict__ betaPtr,
    int M, int Ncol, int K) {
    __shared__ __align__(16) ushort lsA[128 * 64];
    __shared__ __align__(16) ushort lsB[128 * 64];
    const int tid = threadIdx.x;
    const int wave = tid >> 6, lane = tid & 63;
    const int wm = wave >> 1, wn = wave & 1;
    const int l32 = lane & 31, lq = lane >> 5;      // lq in 0..1
    const int m0 = blockIdx.y * 128, n0 = blockIdx.x * 128;

    // staging: lane l of issue (q,wave) writes physical granule
    // g = (q*4+wave)*64 + l  holding global (row = base+(l>>3), c = (l&7)^(l>>3))
    const int srow = lane >> 3;
    const int sgc  = (lane & 7) ^ (lane >> 3);

    v16f acc[2][2] = {};

    for (int k0 = 0; k0 < K; k0 += 64) {
#pragma unroll
        for (int q = 0; q < 4; ++q) {
            const int g0 = (q * 4 + wave) << 6;
            const int row = (g0 >> 3) + srow;
            const ushort* sa = A + (size_t)(m0 + row) * K + k0 + sgc * 8;
            const ushort* sb = B + (size_t)(n0 + row) * K + k0 + sgc * 8;
            __builtin_amdgcn_global_load_lds(GLAS(sa), LDAS(&lsA[g0 * 8]), 16, 0, 0);
            __builtin_amdgcn_global_load_lds(GLAS(sb), LDAS(&lsB[g0 * 8]), 16, 0, 0);
        }
        __syncthreads();
#pragma unroll
        for (int kk = 0; kk < 64; kk += 16) {
            v8bf a[2], b[2];
            const int cbase = (kk >> 3) + lq;        // logical granule col 0..7
#pragma unroll
            for (int i = 0; i < 2; ++i) {
                const int ra = wm * 64 + i * 32 + l32;
                const int pa = ra * 8 + (cbase ^ (ra & 7));
                a[i] = __builtin_bit_cast(v8bf, *(const v4u*)&lsA[pa * 8]);
            }
#pragma unroll
            for (int j = 0; j < 2; ++j) {
                const int rb = wn * 64 + j * 32 + l32;
                const int pb = rb * 8 + (cbase ^ (rb & 7));
                b[j] = __builtin_bit_cast(v8bf, *(const v4u*)&lsB[pb * 8]);
            }
#pragma unroll
            for (int i = 0; i < 2; ++i)
#pragma unroll
                for (int j = 0; j < 2; ++j)
                    acc[i][j] = __builtin_amdgcn_mfma_f32_32x32x16_bf16(a[i], b[j], acc[i][j], 0, 0, 0);
        }
        __syncthreads();
    }

    const float betaV = (EPI == 1) ? betaPtr[0] : 0.f;
#pragma unroll
    for (int j = 0; j < 2; ++j) {
        const int col = n0 + wn * 64 + j * 32 + l32;
        const float bj = bias[col];
#pragma unroll
        for (int i = 0; i < 2; ++i) {
#pragma unroll
            for (int reg = 0; reg < 16; ++reg) {
                const int row = m0 + wm * 64 + i * 32 + (reg & 3) + 8 * (reg >> 2) + 4 * lq;
                float v = acc[i][j][reg] + bj;
                if (EPI == 0) {
                    v = v > 0.f ? v : 0.f;
                    ((ushort*)Cout)[(size_t)row * Ncol + col] = f32_to_bf16(v);
                } else {
                    v += betaV * Y[(size_t)row * Ncol + col];
                    ((float*)Cout)[(size_t)row * Ncol + col] = v;
                }
            }
        }
    }
}

extern "C" void kernel_launch(void* const* d_in, const int* in_sizes, int n_in,
                              void* d_out, int out_size, void* d_ws, size_t ws_size,
                              hipStream_t stream) {
    const float* x    = (const float*)d_in[0];
    const float* y    = (const float*)d_in[1];
    const float* W1   = (const float*)d_in[2];
    const float* b1   = (const float*)d_in[3];
    const float* W2   = (const float*)d_in[4];
    const float* b2   = (const float*)d_in[5];
    const float* bn1g = (const float*)d_in[6];
    const float* bn1b = (const float*)d_in[7];
    const float* bn2g = (const float*)d_in[8];
    const float* bn2b = (const float*)d_in[9];
    const float* beta = (const float*)d_in[10];

    constexpr int Nb = 32768, F = 2048, H = 4096, C = 512;

    char* w = (char*)d_ws;
    ushort* xb  = (ushort*)w;                                       // 128 MB
    ushort* h1  = (ushort*)(w + (size_t)Nb * F * 2);                // 256 MB
    ushort* w1p = (ushort*)(w + (size_t)Nb * F * 2 + (size_t)Nb * H * 2);   // 16 MB
    ushort* w2p = (ushort*)((char*)w1p + (size_t)H * F * 2);        // 4 MB
    float*  fb  = (float*)((char*)w2p + (size_t)C * H * 2);
    float* b1p = fb;            // H
    float* b2p = b1p + H;       // C
    float* sum1 = b2p + C;      // F
    float* ss1  = sum1 + F;     // F
    float* s1   = ss1 + F;      // F
    float* t1   = s1 + F;       // F
    float* sum2 = t1 + F;       // H
    float* ss2  = sum2 + H;     // H
    float* s2   = ss2 + H;      // H
    float* t2   = s2 + H;       // H

    hipMemsetAsync(sum1, 0, sizeof(float) * 2 * F, stream);
    hipMemsetAsync(sum2, 0, sizeof(float) * 2 * H, stream);

    // BN1 stats + x->bf16 (fused): thread = 4 cols; 512 blocks, 128 rows/thread
    colstats_cvt<<<dim3(F / 4 / 256, 256), 256, 0, stream>>>(x, xb, sum1, ss1, F, Nb / 256);
    bn_finalize<<<F / 256, 256, 0, stream>>>(sum1, ss1, bn1g, bn1b, s1, t1, 1.f / Nb);
    // fold BN1 into W1
    fold_w<<<H, 256, 0, stream>>>(W1, b1, s1, t1, w1p, b1p, F);
    // h1 = relu(xb @ w1p^T + b1p), bf16
    gemm_bt<0><<<dim3(H / 128, Nb / 128), 256, 0, stream>>>(xb, w1p, h1, b1p, nullptr, nullptr, Nb, H, F);
    // BN2 stats from h1: thread = 2 cols; 1024 blocks, 256 rows/thread
    colstats_bf16<<<dim3(H / 2 / 256, 128), 256, 0, stream>>>(h1, sum2, ss2, H, Nb / 128);
    bn_finalize<<<H / 256, 256, 0, stream>>>(sum2, ss2, bn2g, bn2b, s2, t2, 1.f / Nb);
    // fold BN2 into W2
    fold_w<<<C, 256, 0, stream>>>(W2, b2, s2, t2, w2p, b2p, H);
    // out = h1 @ w2p^T + b2p + beta*y, fp32
    gemm_bt<1><<<dim3(C / 128, Nb / 128), 256, 0, stream>>>(h1, w2p, d_out, b2p, y, beta, Nb, C, H);
    (void)in_sizes; (void)n_in; (void)out_size; (void)ws_size;
}